// Round 10
// baseline (175.099 us; speedup 1.0000x reference)
//
#include <hip/hip_runtime.h>

#define B_ 64
#define N_ 64
#define D_ 256
#define LAP_ 16
#define M_ 2016           // 64*63/2
#define TOK_ 2081         // 1 + 64 + 2016

typedef float v4f __attribute__((ext_vector_type(4)));

// Map linear upper-tri index m -> (i, j), i<j, row-major over triu(k=1).
__device__ __forceinline__ void ij_from_m(int m, int& i, int& j) {
    float fm = (float)m;
    int gi = (int)((127.0f - sqrtf(127.0f * 127.0f - 8.0f * fm)) * 0.5f);
    if (gi < 0) gi = 0;
    if (gi > 62) gi = 62;
    while (gi > 0 && (127 * gi - gi * gi) / 2 > m) gi--;
    while (gi < 62 && (127 * (gi + 1) - (gi + 1) * (gi + 1)) / 2 <= m) gi++;
    i = gi;
    j = gi + 1 + (m - (127 * gi - gi * gi) / 2);
}

// ---------------------------------------------------------------------------
// Kernel A: role-split prep. Grid (B, 4) = 256 blocks, 256 threads.
// R10 change vs R9: compaction (adj staging + ballot + scan) runs ONCE per
// batch (was 8x redundant); U, V, and node-token production are independent
// roles that never touch adj.
//   role 0: compaction -> src[p]=(i,j,valid), edge mask, head mask
//   role 1: U = eig.W1 (thread owns col t, 64 nodes)
//   role 2: V = eig.W2
//   role 3: node tokens + graph token + base row
//   ws: base[256] | U[B][N][D] | V[B][N][D] | src[B][M] (ints)
// ---------------------------------------------------------------------------
__global__ __launch_bounds__(256, 4) void prep_kernel(
    const int*   __restrict__ adj,
    const float* __restrict__ node_feats,
    const float* __restrict__ eigvec,
    const float* __restrict__ W_lap,
    const float* __restrict__ W_edge,
    const float* __restrict__ b_edge,
    const float* __restrict__ type_embed,
    const float* __restrict__ graph_tok,
    float*       __restrict__ out,
    float*       __restrict__ wsf,
    int*         __restrict__ src)
{
    const int b    = blockIdx.x;
    const int role = blockIdx.y;
    const int t    = threadIdx.x;
    const int wave = t >> 6, lane = t & 63;

    if (role == 0) {
        // ---- compaction: ballot + scan + inverse permutation + masks ----
        __shared__ int sAdj[N_ * N_];              // 16 KB
        __shared__ unsigned long long sWords[32];  // 2016-bit valid mask
        __shared__ int sPref[32];
        __shared__ int sTotal;

#pragma unroll
        for (int r = 0; r < 4; r++)
            ((int4*)sAdj)[r * 256 + t] =
                ((const int4*)(adj + (size_t)b * (N_ * N_)))[r * 256 + t];
        __syncthreads();

#pragma unroll
        for (int k = 0; k < 8; k++) {
            int m = k * 256 + t;
            int valid = 0;
            if (m < M_) {
                int i, j;
                ij_from_m(m, i, j);
                valid = (sAdj[i * N_ + j] > 0) ? 1 : 0;
            }
            unsigned long long blt = __ballot(valid);
            if (lane == 0) sWords[k * 4 + wave] = blt;
        }
        __syncthreads();

        if (t < 32) {
            int cnt = __popcll(sWords[t]);
            int inc = cnt;
#pragma unroll
            for (int off = 1; off < 32; off <<= 1) {
                int v = __shfl_up(inc, off);
                if (lane >= off) inc += v;
            }
            sPref[t] = inc - cnt;
            if (t == 31) sTotal = inc;
        }
        __syncthreads();

        const int total = sTotal;
        float* maskb = out + (size_t)B_ * TOK_ * D_ + (size_t)b * TOK_;
#pragma unroll
        for (int k = 0; k < 8; k++) {
            int m = k * 256 + t;
            if (m < M_) {
                int w = m >> 6, r = m & 63;
                unsigned long long word = sWords[w];
                int rank = sPref[w] + __popcll(word & ((1ull << r) - 1ull));
                int valid = (int)((word >> r) & 1ull);
                int p = valid ? rank : total + (m - rank);
                int i, j;
                ij_from_m(m, i, j);
                src[b * M_ + p] = i | (j << 6) | (valid << 12);
                maskb[1 + N_ + p] = valid ? 0.0f : 1.0f;
            }
        }
        if (t < 1 + N_) maskb[t] = 0.0f;           // mask head
        return;
    }

    // roles 1-3 need eigvec in LDS, never adj
    __shared__ float sEig[N_ * LAP_];              // 4 KB
    ((float4*)sEig)[t] = ((const float4*)(eigvec + (size_t)b * N_ * LAP_))[t];

    if (role == 1 || role == 2) {
        // ---- U or V partials: thread owns col t, all 64 nodes ----
        const float* Wsel = (role == 1) ? (W_edge + D_)
                                        : (W_edge + (1 + LAP_) * D_);
        float wc[LAP_];
#pragma unroll
        for (int l = 0; l < LAP_; l++) wc[l] = Wsel[l * D_ + t];
        __syncthreads();

        float* Tb = wsf + 256 + (size_t)b * N_ * D_
                  + ((role == 2) ? (size_t)B_ * N_ * D_ : 0);
#pragma unroll 4
        for (int n = 0; n < N_; n++) {
            const float* e = sEig + n * LAP_;      // wave-uniform broadcast
            float acc = 0.0f;
#pragma unroll
            for (int l = 0; l < LAP_; l++) acc += e[l] * wc[l];
            Tb[n * D_ + t] = acc;
        }
        return;
    }

    // ---- role 3: node tokens + graph token + base row ----
    float wlc[LAP_];
#pragma unroll
    for (int l = 0; l < LAP_; l++) wlc[l] = W_lap[l * D_ + t];
    __syncthreads();

    float* outB = out + (size_t)b * TOK_ * D_;
#pragma unroll 4
    for (int n = 0; n < N_; n++) {
        float a = node_feats[((size_t)b * N_ + n) * D_ + t];
        const float* e = sEig + n * LAP_;
#pragma unroll
        for (int l = 0; l < LAP_; l++) a += e[l] * wlc[l];
        outB[(size_t)(1 + n) * D_ + t] = a;
    }
    outB[t] = graph_tok[t];                        // graph token
    if (b == 0)
        wsf[t] = W_edge[t] + b_edge[t] + type_embed[D_ + t];  // base row
}

// ---------------------------------------------------------------------------
// Kernel B: destination-ordered edge-token streamer. Grid 2048, 256 threads,
// zero LDS. R10 change: __launch_bounds__(256,4) (128 VGPR, was 64) so the
// unroll-4 loop keeps 4 gather pairs genuinely in flight; 16+ waves/CU
// resident covers store drain.
// ---------------------------------------------------------------------------
__global__ __launch_bounds__(256, 4) void edge_kernel(
    const float* __restrict__ wsf,
    const int*   __restrict__ src,
    float*       __restrict__ out)
{
    const int bid  = blockIdx.x;         // 0..2047
    const int xcd  = bid & 7;
    const int idx  = bid >> 3;           // 0..255
    const int b    = ((idx & 7) << 3) | xcd;   // batch, pinned to XCD b&7
    const int s    = idx >> 3;           // 0..31: dest chunk within batch
    const int wave = threadIdx.x >> 6, lane = threadIdx.x & 63;

    v4f base4 = ((const v4f*)wsf)[lane];
    const float* Ub = wsf + 256 + (size_t)b * N_ * D_;
    const float* Vb = Ub + (size_t)B_ * N_ * D_;
    const int* sb = src + b * M_;
    float* outE = out + (size_t)b * TOK_ * D_ + (size_t)(1 + N_) * D_;

    const int p0 = s * 63;               // this block: dest rows [p0, p0+63)
    // wave handles p = p0 + wave + 4q; prefetch all its infos in one load
    const int q15 = lane & 15;
    const int nq  = (63 - wave + 3) >> 2;          // 16,16,16,15
    int myinfo = (wave + 4 * q15 < 63) ? sb[p0 + wave + 4 * q15] : 0;

#pragma unroll 4
    for (int q = 0; q < nq; q++) {
        int info = __shfl(myinfo, q);    // VALU broadcast, no memory chain
        int p = p0 + wave + 4 * q;
        v4f val = {0.0f, 0.0f, 0.0f, 0.0f};
        if (info & (1 << 12)) {          // wave-uniform branch
            int si = info & 63, di = (info >> 6) & 63;
            v4f u = ((const v4f*)(Ub + si * D_))[lane];
            v4f v = ((const v4f*)(Vb + di * D_))[lane];
            val = base4 + u + v;
        }
        ((v4f*)(outE + (size_t)p * D_))[lane] = val;
    }
}

extern "C" void kernel_launch(void* const* d_in, const int* in_sizes, int n_in,
                              void* d_out, int out_size, void* d_ws, size_t ws_size,
                              hipStream_t stream) {
    const int*   adj        = (const int*)d_in[0];
    const float* node_feats = (const float*)d_in[1];
    const float* eigvec     = (const float*)d_in[2];
    const float* W_lap      = (const float*)d_in[3];
    const float* W_edge     = (const float*)d_in[4];
    const float* b_edge     = (const float*)d_in[5];
    const float* type_embed = (const float*)d_in[6];
    const float* graph_tok  = (const float*)d_in[7];
    float* out = (float*)d_out;

    // ws layout: base[256] | U[B][N][D] | V[B][N][D] | src[B][M] ints  (~8.8 MB)
    float* wsf = (float*)d_ws;
    int*   src = (int*)(wsf + 256 + 2 * (size_t)B_ * N_ * D_);

    prep_kernel<<<dim3(B_, 4), dim3(256), 0, stream>>>(
        adj, node_feats, eigvec, W_lap, W_edge, b_edge, type_embed, graph_tok,
        out, wsf, src);
    edge_kernel<<<dim3(2048), dim3(256), 0, stream>>>(wsf, src, out);
}

// Round 11
// 165.290 us; speedup vs baseline: 1.0593x; 1.0593x over previous
//
#include <hip/hip_runtime.h>

#define B_ 64
#define N_ 64
#define D_ 256
#define LAP_ 16
#define M_ 2016           // 64*63/2
#define TOK_ 2081         // 1 + 64 + 2016

typedef float v4f __attribute__((ext_vector_type(4)));

// Map linear upper-tri index m -> (i, j), i<j, row-major over triu(k=1).
__device__ __forceinline__ void ij_from_m(int m, int& i, int& j) {
    float fm = (float)m;
    int gi = (int)((127.0f - sqrtf(127.0f * 127.0f - 8.0f * fm)) * 0.5f);
    if (gi < 0) gi = 0;
    if (gi > 62) gi = 62;
    while (gi > 0 && (127 * gi - gi * gi) / 2 > m) gi--;
    while (gi < 62 && (127 * (gi + 1) - (gi + 1) * (gi + 1)) / 2 <= m) gi++;
    i = gi;
    j = gi + 1 + (m - (127 * gi - gi * gi) / 2);
}

// ---------------------------------------------------------------------------
// Kernel A: balanced 8-way role-split prep. Grid (B, 8) = 512 blocks (2/CU),
// 256 threads, bounds (256,2) — same grid shape/occupancy as R9 (the 167.7
// config); only the redundancy is removed (R10's 256-block unbalanced split
// regressed).
//   role 0: compaction (adj->LDS, ballot, scan) + src + edge mask + mask head
//   role 1/2: U = eig.W1, nodes [0,32) / [32,64)
//   role 3/4: V = eig.W2, nodes [0,32) / [32,64)
//   role 5/6/7: node tokens, ~21 nodes each; role 5 also graph tok + base row
//   ws: base[256] | U[B][N][D] | V[B][N][D] | src[B][M] (ints)
// Dispatch order (x fastest) keeps bid%8 == b%8, matching edge's XCD pinning.
// ---------------------------------------------------------------------------
__global__ __launch_bounds__(256, 2) void prep_kernel(
    const int*   __restrict__ adj,
    const float* __restrict__ node_feats,
    const float* __restrict__ eigvec,
    const float* __restrict__ W_lap,
    const float* __restrict__ W_edge,
    const float* __restrict__ b_edge,
    const float* __restrict__ type_embed,
    const float* __restrict__ graph_tok,
    float*       __restrict__ out,
    float*       __restrict__ wsf,
    int*         __restrict__ src)
{
    const int b    = blockIdx.x;
    const int role = blockIdx.y;               // 0..7
    const int t    = threadIdx.x;
    const int wave = t >> 6, lane = t & 63;

    if (role == 0) {
        // ---- compaction ----
        __shared__ int sAdj[N_ * N_];              // 16 KB
        __shared__ unsigned long long sWords[32];
        __shared__ int sPref[32];
        __shared__ int sTotal;

#pragma unroll
        for (int r = 0; r < 4; r++)
            ((int4*)sAdj)[r * 256 + t] =
                ((const int4*)(adj + (size_t)b * (N_ * N_)))[r * 256 + t];
        __syncthreads();

#pragma unroll
        for (int k = 0; k < 8; k++) {
            int m = k * 256 + t;
            int valid = 0;
            if (m < M_) {
                int i, j;
                ij_from_m(m, i, j);
                valid = (sAdj[i * N_ + j] > 0) ? 1 : 0;
            }
            unsigned long long blt = __ballot(valid);
            if (lane == 0) sWords[k * 4 + wave] = blt;
        }
        __syncthreads();

        if (t < 32) {
            int cnt = __popcll(sWords[t]);
            int inc = cnt;
#pragma unroll
            for (int off = 1; off < 32; off <<= 1) {
                int v = __shfl_up(inc, off);
                if (lane >= off) inc += v;
            }
            sPref[t] = inc - cnt;
            if (t == 31) sTotal = inc;
        }
        __syncthreads();

        const int total = sTotal;
        float* maskb = out + (size_t)B_ * TOK_ * D_ + (size_t)b * TOK_;
#pragma unroll
        for (int k = 0; k < 8; k++) {
            int m = k * 256 + t;
            if (m < M_) {
                int w = m >> 6, r = m & 63;
                unsigned long long word = sWords[w];
                int rank = sPref[w] + __popcll(word & ((1ull << r) - 1ull));
                int valid = (int)((word >> r) & 1ull);
                int p = valid ? rank : total + (m - rank);
                int i, j;
                ij_from_m(m, i, j);
                src[b * M_ + p] = i | (j << 6) | (valid << 12);
                maskb[1 + N_ + p] = valid ? 0.0f : 1.0f;
            }
        }
        if (t < 1 + N_) maskb[t] = 0.0f;           // mask head
        return;
    }

    // roles 1-7 use eigvec only
    __shared__ float sEig[N_ * LAP_];              // 4 KB
    ((float4*)sEig)[t] = ((const float4*)(eigvec + (size_t)b * N_ * LAP_))[t];

    if (role <= 4) {
        // ---- U (roles 1,2) or V (roles 3,4): 32 nodes, thread owns col t ----
        const int isV = (role >= 3);
        const int n0  = ((role - 1) & 1) * 32;     // 0 or 32
        const float* Wsel = isV ? (W_edge + (1 + LAP_) * D_) : (W_edge + D_);
        float wc[LAP_];
#pragma unroll
        for (int l = 0; l < LAP_; l++) wc[l] = Wsel[l * D_ + t];
        __syncthreads();

        float* Tb = wsf + 256 + (size_t)b * N_ * D_
                  + (isV ? (size_t)B_ * N_ * D_ : 0);
#pragma unroll 4
        for (int k = 0; k < 32; k++) {
            int n = n0 + k;
            const float* e = sEig + n * LAP_;      // wave-uniform broadcast
            float acc = 0.0f;
#pragma unroll
            for (int l = 0; l < LAP_; l++) acc += e[l] * wc[l];
            Tb[n * D_ + t] = acc;
        }
        return;
    }

    // ---- roles 5,6,7: node tokens (21/21/22 nodes) ----
    float wlc[LAP_];
#pragma unroll
    for (int l = 0; l < LAP_; l++) wlc[l] = W_lap[l * D_ + t];
    __syncthreads();

    const int r5 = role - 5;                       // 0,1,2
    const int n0 = r5 * 21;                        // 0,21,42
    const int n1 = (r5 == 2) ? 64 : n0 + 21;
    float* outB = out + (size_t)b * TOK_ * D_;
    for (int n = n0; n < n1; n++) {
        float a = node_feats[((size_t)b * N_ + n) * D_ + t];
        const float* e = sEig + n * LAP_;
#pragma unroll
        for (int l = 0; l < LAP_; l++) a += e[l] * wlc[l];
        outB[(size_t)(1 + n) * D_ + t] = a;
    }
    if (role == 5) {
        outB[t] = graph_tok[t];                    // graph token
        if (b == 0)
            wsf[t] = W_edge[t] + b_edge[t] + type_embed[D_ + t];  // base row
    }
}

// ---------------------------------------------------------------------------
// Kernel B: destination-ordered edge-token streamer — byte-identical to R9.
// Grid 2048, 256 threads, zero LDS, (256,8) -> 32 waves/CU (R10's (256,4)
// halved TLP and regressed; reverted).
// ---------------------------------------------------------------------------
__global__ __launch_bounds__(256, 8) void edge_kernel(
    const float* __restrict__ wsf,
    const int*   __restrict__ src,
    float*       __restrict__ out)
{
    const int bid  = blockIdx.x;         // 0..2047
    const int xcd  = bid & 7;
    const int idx  = bid >> 3;           // 0..255
    const int b    = ((idx & 7) << 3) | xcd;   // batch, pinned to XCD b&7
    const int s    = idx >> 3;           // 0..31: dest chunk within batch
    const int wave = threadIdx.x >> 6, lane = threadIdx.x & 63;

    v4f base4 = ((const v4f*)wsf)[lane];
    const float* Ub = wsf + 256 + (size_t)b * N_ * D_;
    const float* Vb = Ub + (size_t)B_ * N_ * D_;
    const int* sb = src + b * M_;
    float* outE = out + (size_t)b * TOK_ * D_ + (size_t)(1 + N_) * D_;

    const int p0 = s * 63;               // this block: dest rows [p0, p0+63)
    // wave handles p = p0 + wave + 4q; prefetch all its infos in one load
    const int q15 = lane & 15;
    const int nq  = (63 - wave + 3) >> 2;          // 16,16,16,15
    int myinfo = (wave + 4 * q15 < 63) ? sb[p0 + wave + 4 * q15] : 0;

#pragma unroll 4
    for (int q = 0; q < nq; q++) {
        int info = __shfl(myinfo, q);    // VALU broadcast, no memory chain
        int p = p0 + wave + 4 * q;
        v4f val = {0.0f, 0.0f, 0.0f, 0.0f};
        if (info & (1 << 12)) {          // wave-uniform branch
            int si = info & 63, di = (info >> 6) & 63;
            v4f u = ((const v4f*)(Ub + si * D_))[lane];
            v4f v = ((const v4f*)(Vb + di * D_))[lane];
            val = base4 + u + v;
        }
        ((v4f*)(outE + (size_t)p * D_))[lane] = val;
    }
}

extern "C" void kernel_launch(void* const* d_in, const int* in_sizes, int n_in,
                              void* d_out, int out_size, void* d_ws, size_t ws_size,
                              hipStream_t stream) {
    const int*   adj        = (const int*)d_in[0];
    const float* node_feats = (const float*)d_in[1];
    const float* eigvec     = (const float*)d_in[2];
    const float* W_lap      = (const float*)d_in[3];
    const float* W_edge     = (const float*)d_in[4];
    const float* b_edge     = (const float*)d_in[5];
    const float* type_embed = (const float*)d_in[6];
    const float* graph_tok  = (const float*)d_in[7];
    float* out = (float*)d_out;

    // ws layout: base[256] | U[B][N][D] | V[B][N][D] | src[B][M] ints  (~8.8 MB)
    float* wsf = (float*)d_ws;
    int*   src = (int*)(wsf + 256 + 2 * (size_t)B_ * N_ * D_);

    prep_kernel<<<dim3(B_, 8), dim3(256), 0, stream>>>(
        adj, node_feats, eigvec, W_lap, W_edge, b_edge, type_embed, graph_tok,
        out, wsf, src);
    edge_kernel<<<dim3(2048), dim3(256), 0, stream>>>(wsf, src, out);
}

// Round 12
// 163.833 us; speedup vs baseline: 1.0688x; 1.0089x over previous
//
#include <hip/hip_runtime.h>

#define B_ 64
#define N_ 64
#define D_ 256
#define LAP_ 16
#define M_ 2016           // 64*63/2
#define TOK_ 2081         // 1 + 64 + 2016

typedef float v4f __attribute__((ext_vector_type(4)));

// Map linear upper-tri index m -> (i, j), i<j, row-major over triu(k=1).
__device__ __forceinline__ void ij_from_m(int m, int& i, int& j) {
    float fm = (float)m;
    int gi = (int)((127.0f - sqrtf(127.0f * 127.0f - 8.0f * fm)) * 0.5f);
    if (gi < 0) gi = 0;
    if (gi > 62) gi = 62;
    while (gi > 0 && (127 * gi - gi * gi) / 2 > m) gi--;
    while (gi < 62 && (127 * (gi + 1) - (gi + 1) * (gi + 1)) / 2 <= m) gi++;
    i = gi;
    j = gi + 1 + (m - (127 * gi - gi * gi) / 2);
}

// ---------------------------------------------------------------------------
// Kernel A: 16-way role-split prep. Grid (B, 16) = 1024 blocks (4/CU,
// 16 waves/CU — R12: double R11's TLP, half the per-block work).
//   role 0    : compaction (adj->LDS, ballot, scan, src, edge mask, mask head)
//   roles 1-4 : U = eig.W1, 16 nodes each
//   roles 5-8 : V = eig.W2, 16 nodes each
//   roles 9-15: node tokens, 9-10 nodes each; role 9 also graph tok + base row
//   ws: base[256] | U[B][N][D] | V[B][N][D] | src[B][M] (ints)
// bid%8 == b%8 for every role -> whole batch pinned to XCD b%8, matching
// edge_kernel's pinning (adj/eigvec/U/V stay in one L2).
// ---------------------------------------------------------------------------
__global__ __launch_bounds__(256, 2) void prep_kernel(
    const int*   __restrict__ adj,
    const float* __restrict__ node_feats,
    const float* __restrict__ eigvec,
    const float* __restrict__ W_lap,
    const float* __restrict__ W_edge,
    const float* __restrict__ b_edge,
    const float* __restrict__ type_embed,
    const float* __restrict__ graph_tok,
    float*       __restrict__ out,
    float*       __restrict__ wsf,
    int*         __restrict__ src)
{
    const int b    = blockIdx.x;
    const int role = blockIdx.y;               // 0..15
    const int t    = threadIdx.x;
    const int wave = t >> 6, lane = t & 63;

    if (role == 0) {
        // ---- compaction ----
        __shared__ int sAdj[N_ * N_];              // 16 KB
        __shared__ unsigned long long sWords[32];
        __shared__ int sPref[32];
        __shared__ int sTotal;

#pragma unroll
        for (int r = 0; r < 4; r++)
            ((int4*)sAdj)[r * 256 + t] =
                ((const int4*)(adj + (size_t)b * (N_ * N_)))[r * 256 + t];
        __syncthreads();

#pragma unroll
        for (int k = 0; k < 8; k++) {
            int m = k * 256 + t;
            int valid = 0;
            if (m < M_) {
                int i, j;
                ij_from_m(m, i, j);
                valid = (sAdj[i * N_ + j] > 0) ? 1 : 0;
            }
            unsigned long long blt = __ballot(valid);
            if (lane == 0) sWords[k * 4 + wave] = blt;
        }
        __syncthreads();

        if (t < 32) {
            int cnt = __popcll(sWords[t]);
            int inc = cnt;
#pragma unroll
            for (int off = 1; off < 32; off <<= 1) {
                int v = __shfl_up(inc, off);
                if (lane >= off) inc += v;
            }
            sPref[t] = inc - cnt;
            if (t == 31) sTotal = inc;
        }
        __syncthreads();

        const int total = sTotal;
        float* maskb = out + (size_t)B_ * TOK_ * D_ + (size_t)b * TOK_;
#pragma unroll
        for (int k = 0; k < 8; k++) {
            int m = k * 256 + t;
            if (m < M_) {
                int w = m >> 6, r = m & 63;
                unsigned long long word = sWords[w];
                int rank = sPref[w] + __popcll(word & ((1ull << r) - 1ull));
                int valid = (int)((word >> r) & 1ull);
                int p = valid ? rank : total + (m - rank);
                int i, j;
                ij_from_m(m, i, j);
                src[b * M_ + p] = i | (j << 6) | (valid << 12);
                maskb[1 + N_ + p] = valid ? 0.0f : 1.0f;
            }
        }
        if (t < 1 + N_) maskb[t] = 0.0f;           // mask head
        return;
    }

    // roles 1-15 use eigvec only
    __shared__ float sEig[N_ * LAP_];              // 4 KB
    ((float4*)sEig)[t] = ((const float4*)(eigvec + (size_t)b * N_ * LAP_))[t];

    if (role <= 8) {
        // ---- U (roles 1-4) or V (roles 5-8): 16 nodes, thread owns col t ----
        const int isV = (role >= 5);
        const int n0  = (isV ? (role - 5) : (role - 1)) * 16;
        const float* Wsel = isV ? (W_edge + (1 + LAP_) * D_) : (W_edge + D_);
        float wc[LAP_];
#pragma unroll
        for (int l = 0; l < LAP_; l++) wc[l] = Wsel[l * D_ + t];
        __syncthreads();

        float* Tb = wsf + 256 + (size_t)b * N_ * D_
                  + (isV ? (size_t)B_ * N_ * D_ : 0);
#pragma unroll 4
        for (int k = 0; k < 16; k++) {
            int n = n0 + k;
            const float* e = sEig + n * LAP_;      // wave-uniform broadcast
            float acc = 0.0f;
#pragma unroll
            for (int l = 0; l < LAP_; l++) acc += e[l] * wc[l];
            Tb[n * D_ + t] = acc;
        }
        return;
    }

    // ---- roles 9-15: node tokens (9-10 nodes each) ----
    float wlc[LAP_];
#pragma unroll
    for (int l = 0; l < LAP_; l++) wlc[l] = W_lap[l * D_ + t];
    __syncthreads();

    const int r9 = role - 9;                       // 0..6
    const int n0 = r9 * 9;                         // 0,9,..,54
    const int n1 = (r9 == 6) ? 64 : n0 + 9;
    float* outB = out + (size_t)b * TOK_ * D_;
    for (int n = n0; n < n1; n++) {
        float a = node_feats[((size_t)b * N_ + n) * D_ + t];
        const float* e = sEig + n * LAP_;
#pragma unroll
        for (int l = 0; l < LAP_; l++) a += e[l] * wlc[l];
        outB[(size_t)(1 + n) * D_ + t] = a;
    }
    if (role == 9) {
        outB[t] = graph_tok[t];                    // graph token
        if (b == 0)
            wsf[t] = W_edge[t] + b_edge[t] + type_embed[D_ + t];  // base row
    }
}

// ---------------------------------------------------------------------------
// Kernel B: destination-ordered edge-token streamer — byte-identical to
// R9/R11. Grid 2048, 256 threads, zero LDS, (256,8) -> 32 waves/CU.
// ---------------------------------------------------------------------------
__global__ __launch_bounds__(256, 8) void edge_kernel(
    const float* __restrict__ wsf,
    const int*   __restrict__ src,
    float*       __restrict__ out)
{
    const int bid  = blockIdx.x;         // 0..2047
    const int xcd  = bid & 7;
    const int idx  = bid >> 3;           // 0..255
    const int b    = ((idx & 7) << 3) | xcd;   // batch, pinned to XCD b&7
    const int s    = idx >> 3;           // 0..31: dest chunk within batch
    const int wave = threadIdx.x >> 6, lane = threadIdx.x & 63;

    v4f base4 = ((const v4f*)wsf)[lane];
    const float* Ub = wsf + 256 + (size_t)b * N_ * D_;
    const float* Vb = Ub + (size_t)B_ * N_ * D_;
    const int* sb = src + b * M_;
    float* outE = out + (size_t)b * TOK_ * D_ + (size_t)(1 + N_) * D_;

    const int p0 = s * 63;               // this block: dest rows [p0, p0+63)
    // wave handles p = p0 + wave + 4q; prefetch all its infos in one load
    const int q15 = lane & 15;
    const int nq  = (63 - wave + 3) >> 2;          // 16,16,16,15
    int myinfo = (wave + 4 * q15 < 63) ? sb[p0 + wave + 4 * q15] : 0;

#pragma unroll 4
    for (int q = 0; q < nq; q++) {
        int info = __shfl(myinfo, q);    // VALU broadcast, no memory chain
        int p = p0 + wave + 4 * q;
        v4f val = {0.0f, 0.0f, 0.0f, 0.0f};
        if (info & (1 << 12)) {          // wave-uniform branch
            int si = info & 63, di = (info >> 6) & 63;
            v4f u = ((const v4f*)(Ub + si * D_))[lane];
            v4f v = ((const v4f*)(Vb + di * D_))[lane];
            val = base4 + u + v;
        }
        ((v4f*)(outE + (size_t)p * D_))[lane] = val;
    }
}

extern "C" void kernel_launch(void* const* d_in, const int* in_sizes, int n_in,
                              void* d_out, int out_size, void* d_ws, size_t ws_size,
                              hipStream_t stream) {
    const int*   adj        = (const int*)d_in[0];
    const float* node_feats = (const float*)d_in[1];
    const float* eigvec     = (const float*)d_in[2];
    const float* W_lap      = (const float*)d_in[3];
    const float* W_edge     = (const float*)d_in[4];
    const float* b_edge     = (const float*)d_in[5];
    const float* type_embed = (const float*)d_in[6];
    const float* graph_tok  = (const float*)d_in[7];
    float* out = (float*)d_out;

    // ws layout: base[256] | U[B][N][D] | V[B][N][D] | src[B][M] ints  (~8.8 MB)
    float* wsf = (float*)d_ws;
    int*   src = (int*)(wsf + 256 + 2 * (size_t)B_ * N_ * D_);

    prep_kernel<<<dim3(B_, 16), dim3(256), 0, stream>>>(
        adj, node_feats, eigvec, W_lap, W_edge, b_edge, type_embed, graph_tok,
        out, wsf, src);
    edge_kernel<<<dim3(2048), dim3(256), 0, stream>>>(wsf, src, out);
}